// Round 2
// baseline (403.239 us; speedup 1.0000x reference)
//
#include <hip/hip_runtime.h>
#include <stdint.h>

// out[b,m,f] = sum_n x[b,n,f] * (support[n,m]*kernel[n,m]) + bias[f]
// support = 3-hop ring mask -> 7 nonzeros/column. Build a column-compacted
// (CSC) form PADDED to TAPS=8 slots so the hot kernel has a compile-time
// unrolled tap loop: scalar (wave-uniform) weight loads + 8 independent
// float4 x-loads in flight (MLP=8, vs serialized runtime loop in round 1
// which was latency-bound at 2.4 TB/s).

#define TAPS 8

__global__ void build_csc_kernel(const float* __restrict__ support,
                                 const float* __restrict__ kern,
                                 int* __restrict__ cnt,
                                 int* __restrict__ idx,
                                 float* __restrict__ val,
                                 int* __restrict__ pidx,
                                 float* __restrict__ pval,
                                 int n) {
    const int m = blockIdx.x;      // one column per block
    const int lane = threadIdx.x;  // 64 threads = one wave
    int base = 0;
    for (int n0 = 0; n0 < n; n0 += 64) {
        const int row = n0 + lane;
        float w = 0.0f;
        if (row < n) w = support[(size_t)row * n + m] * kern[(size_t)row * n + m];
        const unsigned long long mask = __ballot(w != 0.0f);
        const int pos = base + (int)__popcll(mask & ((1ull << lane) - 1ull));
        if (w != 0.0f) {
            idx[(size_t)m * n + pos] = row;
            val[(size_t)m * n + pos] = w;
            if (pos < TAPS) { pidx[m * TAPS + pos] = row; pval[m * TAPS + pos] = w; }
        }
        base += (int)__popcll(mask);
    }
    // pad unused tap slots: row 0 (always valid) with weight 0
    if (lane >= base && lane < TAPS) { pidx[m * TAPS + lane] = 0; pval[m * TAPS + lane] = 0.0f; }
    if (lane == 0) cnt[m] = base;
}

__global__ __launch_bounds__(256) void spmm_kernel(
    const float4* __restrict__ x, const float* __restrict__ bias,
    const int* __restrict__ cnt,
    const int* __restrict__ pidx, const float* __restrict__ pval,
    const int* __restrict__ idx, const float* __restrict__ val,
    float4* __restrict__ out,
    int n, int f4, int swizzle) {
    const int blk = blockIdx.x;
    int b, m;
    if (swizzle) {
        // all m-blocks of one batch b land on one XCD, consecutively
        const int xcd = blk & 7;
        const int ii = blk >> 3;
        b = xcd + 8 * (ii / n);
        m = ii % n;
    } else {
        b = blk / n;
        m = blk % n;
    }
    const int c = cnt[m];
    const float4* __restrict__ b4 = (const float4*)bias;
    const size_t xbase = (size_t)b * n * f4;
    const size_t obase = ((size_t)b * n + m) * f4;

    if (c <= TAPS) {
        // fast path: compile-time tap count, scalar weight loads
        int rows[TAPS];
        float w[TAPS];
#pragma unroll
        for (int j = 0; j < TAPS; ++j) {
            rows[j] = pidx[m * TAPS + j];   // wave-uniform -> s_load
            w[j]    = pval[m * TAPS + j];
        }
        for (int t = threadIdx.x; t < f4; t += 256) {
            float4 v[TAPS];
#pragma unroll
            for (int j = 0; j < TAPS; ++j)
                v[j] = x[xbase + (size_t)rows[j] * f4 + t];   // 8 loads in flight
            float4 acc = b4[t];
#pragma unroll
            for (int j = 0; j < TAPS; ++j) {
                acc.x = fmaf(w[j], v[j].x, acc.x);
                acc.y = fmaf(w[j], v[j].y, acc.y);
                acc.z = fmaf(w[j], v[j].z, acc.z);
                acc.w = fmaf(w[j], v[j].w, acc.w);
            }
            out[obase + t] = acc;
        }
    } else {
        // generic fallback (never hit for 3-hop ring, kept for correctness)
        const int* __restrict__ ip = idx + (size_t)m * n;
        const float* __restrict__ vp = val + (size_t)m * n;
        for (int t = threadIdx.x; t < f4; t += 256) {
            float4 acc = b4[t];
            for (int j = 0; j < c; ++j) {
                const int nn = ip[j];
                const float wj = vp[j];
                const float4 v = x[xbase + (size_t)nn * f4 + t];
                acc.x = fmaf(wj, v.x, acc.x);
                acc.y = fmaf(wj, v.y, acc.y);
                acc.z = fmaf(wj, v.z, acc.z);
                acc.w = fmaf(wj, v.w, acc.w);
            }
            out[obase + t] = acc;
        }
    }
}

// Correctness fallback if d_ws is too small for the CSC arrays (unlikely).
__global__ __launch_bounds__(256) void dense_fallback_kernel(
    const float4* __restrict__ x, const float* __restrict__ support,
    const float* __restrict__ kern, const float* __restrict__ bias,
    float4* __restrict__ out, int n, int f4) {
    const int blk = blockIdx.x;
    const int b = blk / n;
    const int m = blk % n;
    const float4* __restrict__ b4 = (const float4*)bias;
    const size_t xbase = (size_t)b * n * f4;
    const size_t obase = ((size_t)b * n + m) * f4;
    for (int t = threadIdx.x; t < f4; t += 256) {
        float4 acc = b4[t];
        for (int nn = 0; nn < n; ++nn) {
            const float w = support[(size_t)nn * n + m] * kern[(size_t)nn * n + m];
            if (w != 0.0f) {
                const float4 v = x[xbase + (size_t)nn * f4 + t];
                acc.x = fmaf(w, v.x, acc.x);
                acc.y = fmaf(w, v.y, acc.y);
                acc.z = fmaf(w, v.z, acc.z);
                acc.w = fmaf(w, v.w, acc.w);
            }
        }
        out[obase + t] = acc;
    }
}

extern "C" void kernel_launch(void* const* d_in, const int* in_sizes, int n_in,
                              void* d_out, int out_size, void* d_ws, size_t ws_size,
                              hipStream_t stream) {
    const float* x       = (const float*)d_in[0];
    const float* support = (const float*)d_in[1];
    const float* kern    = (const float*)d_in[2];
    const float* bias    = (const float*)d_in[3];
    float* out = (float*)d_out;

    // n from support (n*n elements); f from bias; batch from x.
    const int nsq = in_sizes[1];
    int n = 1;
    while (n * n < nsq) ++n;          // n = 199
    const int f = in_sizes[3];        // 1024
    const int f4 = f / 4;             // 256
    const int batch = in_sizes[0] / (n * f);  // 256

    const size_t need = ((size_t)n + 2u * (size_t)n * (size_t)n
                         + 2u * (size_t)n * TAPS) * 4u;
    if (ws_size >= need && (f % 4) == 0) {
        int* cnt = (int*)d_ws;
        int* idx = cnt + n;
        float* val = (float*)(idx + (size_t)n * n);
        int* pidx = (int*)(val + (size_t)n * n);
        float* pval = (float*)(pidx + (size_t)n * TAPS);
        build_csc_kernel<<<n, 64, 0, stream>>>(support, kern, cnt, idx, val,
                                               pidx, pval, n);
        const int swz = (batch % 8 == 0) ? 1 : 0;
        spmm_kernel<<<batch * n, 256, 0, stream>>>(
            (const float4*)x, bias, cnt, pidx, pval, idx, val,
            (float4*)out, n, f4, swz);
    } else {
        dense_fallback_kernel<<<batch * n, 256, 0, stream>>>(
            (const float4*)x, support, kern, bias, (float4*)out, n, f / 4);
    }
}